// Round 11
// baseline (314.414 us; speedup 1.0000x reference)
//
#include <hip/hip_runtime.h>
#include <hip/hip_bf16.h>

#define NPOS 784
#define WDIM 28

// ---- bf16 pack/unpack (RNE) ----
__device__ __forceinline__ unsigned int f2bf(float f) {
    union { float f; unsigned int u; } v; v.f = f;
    unsigned int r = v.u + 0x7fffu + ((v.u >> 16) & 1u);
    return r >> 16;
}
__device__ __forceinline__ float bflo(unsigned int p) {
    union { unsigned int u; float f; } v; v.u = p << 16; return v.f;
}

// ---------------- kernel 1: fused 1x1-conv q/k/v -> d_ws ----------------
// All fp32. Layout [bh][kl][m], m contiguous (16 floats = 64 B per row).
__global__ __launch_bounds__(256) void qkv_kernel(
    const float* __restrict__ x,
    const float* __restrict__ wq, const float* __restrict__ bq,
    const float* __restrict__ wk, const float* __restrict__ bk,
    const float* __restrict__ wv, const float* __restrict__ bv,
    float* __restrict__ Q, float* __restrict__ K, float* __restrict__ V)
{
    int idx = blockIdx.x * 256 + threadIdx.x;        // grid covers exactly 401408
    int ij = idx % NPOS;
    int oc = (idx / NPOS) & 127;
    int b  = idx / (NPOS * 128);

    float x0 = x[(b * 3 + 0) * NPOS + ij];
    float x1 = x[(b * 3 + 1) * NPOS + ij];
    float x2 = x[(b * 3 + 2) * NPOS + ij];

    float q = bq[oc] + wq[oc*3+0]*x0 + wq[oc*3+1]*x1 + wq[oc*3+2]*x2;
    float k = bk[oc] + wk[oc*3+0]*x0 + wk[oc*3+1]*x1 + wk[oc*3+2]*x2;
    float v = bv[oc] + wv[oc*3+0]*x0 + wv[oc*3+1]*x1 + wv[oc*3+2]*x2;

    int m = oc >> 3, h = oc & 7;                     // oc = m*HEADS + h
    int dst = ((b * 8 + h) * NPOS + ij) * 16 + m;
    Q[dst] = q; K[dst] = k; V[dst] = v;
}

// ---------------- kernel 2: attention, block = (b, ij), XCD-swizzled ----------------
// Wave w owns heads {w, w+4}; no barriers in the head loop. Factorized
// softmax: p_g = ec[k] * er[g] * ecol[(g+1)&3] (constants cancel in the
// normalization). ec strip stored bf16 (halves LDS -> 8 blocks/CU).
__global__ __launch_bounds__(256, 4) void attn_kernel(
    const float* __restrict__ Q, const float* __restrict__ K, const float* __restrict__ V,
    const float* __restrict__ w_out, const float* __restrict__ b_out,
    const float* __restrict__ rw1, const float* __restrict__ rb1,
    const float* __restrict__ rga, const float* __restrict__ rbe,
    const float* __restrict__ rw2, const float* __restrict__ rb2,
    const float* __restrict__ cw1, const float* __restrict__ cb1,
    const float* __restrict__ cga, const float* __restrict__ cbe,
    const float* __restrict__ cw2, const float* __restrict__ cb2,
    float* __restrict__ out)
{
    __shared__ float          Er[8 * 110], Ec[8 * 110]; // embed tables, transposed [m][d]
    __shared__ unsigned short conth[4][800];            // [wave][ch*50 + s]: bf16 c, then ec
    __shared__ float4         RtE[4][56];               // exp'ed rotation terms per wave
    __shared__ float          ovs[8][4][16];            // [h][g][m]

    const int t    = threadIdx.x;
    // XCD-aware swizzle: consecutive blockIdx round-robin XCDs; keep each
    // XCD mostly on one batch's K/V (1.2 MB << 4 MB per-XCD L2).
    const int b    = (blockIdx.x >> 1) & 3;
    const int ij   = (blockIdx.x >> 3) * 2 + (blockIdx.x & 1);
    const int iq   = ij / WDIM, jq = ij % WDIM;
    const int wave = t >> 6, lane = t & 63;
    const float scale = 0.57735026918962576f;        // 1/sqrt(CIN=3)

    // ---- embedding-MLP tables (once per block), transposed to [m][110] ----
    {
        int d = -1;
        const float *w1 = rw1, *b1 = rb1, *ga = rga, *be = rbe, *w2 = rw2, *b2 = rb2;
        float* E = Er;
        if (t < 110) { d = t; }
        else if (t >= 128 && t < 238) { d = t - 128; w1 = cw1; b1 = cb1; ga = cga; be = cbe; w2 = cw2; b2 = cb2; E = Ec; }
        if (d >= 0) {
            float u = (d < 55) ? (-1.0f + (float)d * (2.0f / 54.0f))
                               : -(-1.0f + (float)(d - 55) * (2.0f / 54.0f));
            float hb[16], mu = 0.0f;
#pragma unroll
            for (int c = 0; c < 16; ++c) { hb[c] = u * w1[c] + b1[c]; mu += hb[c]; }
            mu *= (1.0f / 16.0f);
            float var = 0.0f;
#pragma unroll
            for (int c = 0; c < 16; ++c) { float dv = hb[c] - mu; var += dv * dv; }
            var *= (1.0f / 16.0f);
            float rstd = rsqrtf(var + 1e-5f);
#pragma unroll
            for (int c = 0; c < 16; ++c) {
                float hn = ga[c] * (hb[c] - mu) * rstd + be[c];
                hb[c] = hn / (1.0f + __expf(-hn));
            }
#pragma unroll
            for (int m = 0; m < 8; ++m) {
                float e = b2[m];
#pragma unroll
                for (int c = 0; c < 16; ++c) e += hb[c] * w2[m * 16 + c];
                E[m * 110 + d] = e;                  // transposed
            }
        }
    }
    __syncthreads();                                 // E ready for all waves

    for (int hi = 0; hi < 2; ++hi) {
        const int h  = wave + hi * 4;
        const int bh = b * 8 + h;

        // q in registers (wave-uniform loads, L2-hot)
        float q[16];
        {
            const float4* qp = (const float4*)(Q + (size_t)(bh * NPOS + ij) * 16);
            float4 q0 = qp[0], q1 = qp[1], q2 = qp[2], q3 = qp[3];
            q[0]=q0.x; q[1]=q0.y; q[2]=q0.z; q[3]=q0.w;
            q[4]=q1.x; q[5]=q1.y; q[6]=q1.z; q[7]=q1.w;
            q[8]=q2.x; q[9]=q2.y; q[10]=q2.z; q[11]=q2.w;
            q[12]=q3.x; q[13]=q3.y; q[14]=q3.z; q[15]=q3.w;
        }

        // rotation terms (scaled) + per-component maxima -> exp'ed table
        float4 mine = make_float4(-3.0e38f, -3.0e38f, -3.0e38f, -3.0e38f);
        if (lane < 55) {
            int d = lane;
            float ar = 0, ac = 0, ar5 = 0, ac5 = 0;
#pragma unroll
            for (int mm = 0; mm < 8; ++mm) {
                float ql = q[mm], qh = q[8 + mm];
                ar  += ql * Er[mm * 110 + d];
                ar5 += ql * Er[mm * 110 + d + 55];
                ac  += qh * Ec[mm * 110 + d];
                ac5 += qh * Ec[mm * 110 + d + 55];
            }
            mine = make_float4(ar * scale, ac * scale, ar5 * scale, ac5 * scale);
        }
        float4 mx = mine;
#pragma unroll
        for (int off = 1; off < 64; off <<= 1) {
            mx.x = fmaxf(mx.x, __shfl_xor(mx.x, off, 64));
            mx.y = fmaxf(mx.y, __shfl_xor(mx.y, off, 64));
            mx.z = fmaxf(mx.z, __shfl_xor(mx.z, off, 64));
            mx.w = fmaxf(mx.w, __shfl_xor(mx.w, off, 64));
        }
        if (lane < 55)
            RtE[wave][lane] = make_float4(__expf(mine.x - mx.x), __expf(mine.y - mx.y),
                                          __expf(mine.z - mx.z), __expf(mine.w - mx.w));

        // content pass -> bf16 strip conth[ch*50+s]; track max
        float maxc = -3.0e38f;
#pragma unroll 4
        for (int it = 0; it < 13; ++it) {
            int k = it * 64 + lane;
            if (k < NPOS) {
                const float4* kp = (const float4*)(K + (size_t)(bh * NPOS + k) * 16);
                float4 k0 = kp[0], k1 = kp[1], k2 = kp[2], k3 = kp[3];
                float c = q[0]*k0.x + q[1]*k0.y + q[2]*k0.z + q[3]*k0.w
                        + q[4]*k1.x + q[5]*k1.y + q[6]*k1.z + q[7]*k1.w
                        + q[8]*k2.x + q[9]*k2.y + q[10]*k2.z + q[11]*k2.w
                        + q[12]*k3.x + q[13]*k3.y + q[14]*k3.z + q[15]*k3.w;
                c *= scale;
                conth[wave][(k & 15) * 50 + (k >> 4)] = (unsigned short)f2bf(c);
                maxc = fmaxf(maxc, c);
            }
        }
#pragma unroll
        for (int off = 1; off < 64; off <<= 1) maxc = fmaxf(maxc, __shfl_xor(maxc, off, 64));

        // exp-ify the strip (same-wave RMW, in-order, no barrier)
#pragma unroll 4
        for (int it = 0; it < 13; ++it) {
            int idx = it * 64 + lane;
            if (idx < 800) {
                float cv = bflo((unsigned int)conth[wave][idx]);
                conth[wave][idx] = (unsigned short)f2bf(__expf(cv - maxc));
            }
        }

        // PV: lane = (vq, ch); keys k = s*16+ch; 3 mults per p, no exp.
        const int vq = lane >> 4, ch = lane & 15;
        const unsigned short* ecw = &conth[wave][ch * 50];
        const float4* RtEp = &RtE[wave][0];
        float acc[4][4];
#pragma unroll
        for (int g = 0; g < 4; ++g)
#pragma unroll
            for (int c = 0; c < 4; ++c) acc[g][c] = 0.0f;
        float ps0 = 0, ps1 = 0, ps2 = 0, ps3 = 0;
#pragma unroll 4
        for (int s = 0; s < 49; ++s) {
            int k   = s * 16 + ch;
            int row = (k * 2341) >> 16;              // k / 28 (exact for k < 784)
            int col = k - row * WDIM;
            float  ec   = bflo((unsigned int)ecw[s]);
            float4 er   = RtEp[row - iq + 27];
            float4 ecol = RtEp[col - jq + 27];
            float p0 = ec * er.x * ecol.y;
            float p1 = ec * er.y * ecol.z;
            float p2 = ec * er.z * ecol.w;
            float p3 = ec * er.w * ecol.x;
            ps0 += p0; ps1 += p1; ps2 += p2; ps3 += p3;
            float4 v = ((const float4*)(V + (size_t)(bh * NPOS + k) * 16))[vq];
            acc[0][0] += p0*v.x; acc[0][1] += p0*v.y; acc[0][2] += p0*v.z; acc[0][3] += p0*v.w;
            acc[1][0] += p1*v.x; acc[1][1] += p1*v.y; acc[1][2] += p1*v.z; acc[1][3] += p1*v.w;
            acc[2][0] += p2*v.x; acc[2][1] += p2*v.y; acc[2][2] += p2*v.z; acc[2][3] += p2*v.w;
            acc[3][0] += p3*v.x; acc[3][1] += p3*v.y; acc[3][2] += p3*v.z; acc[3][3] += p3*v.w;
        }
        // reduce over the 16 ch lanes (xor stays within each vq group)
#pragma unroll
        for (int off = 1; off < 16; off <<= 1) {
            ps0 += __shfl_xor(ps0, off, 64); ps1 += __shfl_xor(ps1, off, 64);
            ps2 += __shfl_xor(ps2, off, 64); ps3 += __shfl_xor(ps3, off, 64);
#pragma unroll
            for (int g = 0; g < 4; ++g)
#pragma unroll
                for (int c = 0; c < 4; ++c) acc[g][c] += __shfl_xor(acc[g][c], off, 64);
        }
        if (ch == 0) {
            float inv0 = 1.0f / ps0, inv1 = 1.0f / ps1, inv2 = 1.0f / ps2, inv3 = 1.0f / ps3;
#pragma unroll
            for (int c = 0; c < 4; ++c) {
                ovs[h][0][vq * 4 + c] = acc[0][c] * inv0;
                ovs[h][1][vq * 4 + c] = acc[1][c] * inv1;
                ovs[h][2][vq * 4 + c] = acc[2][c] * inv2;
                ovs[h][3][vq * 4 + c] = acc[3][c] * inv3;
            }
        }
    }
    __syncthreads();                                 // all ovs ready

    // ---- output projection: thread = (o = t>>2, g = t&3); out (B,64,G,28,28) ----
    {
        int o = t >> 2, g = t & 3;
        float acc = b_out[o];
        const float4* wr = (const float4*)(w_out + o * 128);
#pragma unroll
        for (int c4 = 0; c4 < 32; ++c4) {
            float4 w4 = wr[c4];
            int c = c4 * 4;                          // mh = m*8 + h
            acc += w4.x * ovs[(c    ) & 7][g][(c    ) >> 3];
            acc += w4.y * ovs[(c + 1) & 7][g][(c + 1) >> 3];
            acc += w4.z * ovs[(c + 2) & 7][g][(c + 2) >> 3];
            acc += w4.w * ovs[(c + 3) & 7][g][(c + 3) >> 3];
        }
        out[((b * 64 + o) * 4 + g) * NPOS + ij] = acc;
    }
}

extern "C" void kernel_launch(void* const* d_in, const int* in_sizes, int n_in,
                              void* d_out, int out_size, void* d_ws, size_t ws_size,
                              hipStream_t stream)
{
    const float* x     = (const float*)d_in[0];
    const float* wq    = (const float*)d_in[1];
    const float* bq    = (const float*)d_in[2];
    const float* wk    = (const float*)d_in[3];
    const float* bk    = (const float*)d_in[4];
    const float* wv    = (const float*)d_in[5];
    const float* bv    = (const float*)d_in[6];
    const float* w_out = (const float*)d_in[7];
    const float* b_out = (const float*)d_in[8];
    const float* rw1 = (const float*)d_in[9];
    const float* rb1 = (const float*)d_in[10];
    const float* rga = (const float*)d_in[11];
    const float* rbe = (const float*)d_in[12];
    const float* rw2 = (const float*)d_in[13];
    const float* rb2 = (const float*)d_in[14];
    const float* cw1 = (const float*)d_in[15];
    const float* cb1 = (const float*)d_in[16];
    const float* cga = (const float*)d_in[17];
    const float* cbe = (const float*)d_in[18];
    const float* cw2 = (const float*)d_in[19];
    const float* cb2 = (const float*)d_in[20];
    // d_in[21]/d_in[22] (ridx/cidx) unused: closed-form rotation indices.

    float* Q = (float*)d_ws;                 // 3 x 401408 floats = 4.8 MB
    float* K = Q + 401408;
    float* V = K + 401408;

    qkv_kernel<<<1568, 256, 0, stream>>>(x, wq, bq, wk, bk, wv, bv, Q, K, V);
    attn_kernel<<<4 * NPOS, 256, 0, stream>>>(
        Q, K, V, w_out, b_out,
        rw1, rb1, rga, rbe, rw2, rb2,
        cw1, cb1, cga, cbe, cw2, cb2,
        (float*)d_out);
}

// Round 12
// 314.033 us; speedup vs baseline: 1.0012x; 1.0012x over previous
//
#include <hip/hip_runtime.h>
#include <hip/hip_bf16.h>

#define NPOS 784
#define WDIM 28

// ---- bf16 pack/unpack (RNE) ----
__device__ __forceinline__ unsigned int f2bf(float f) {
    union { float f; unsigned int u; } v; v.f = f;
    unsigned int r = v.u + 0x7fffu + ((v.u >> 16) & 1u);
    return r >> 16;
}
__device__ __forceinline__ float bflo(unsigned int p) {
    union { unsigned int u; float f; } v; v.u = p << 16; return v.f;
}

// ---------------- kernel 1: fused 1x1-conv q/k/v -> d_ws ----------------
__global__ __launch_bounds__(256) void qkv_kernel(
    const float* __restrict__ x,
    const float* __restrict__ wq, const float* __restrict__ bq,
    const float* __restrict__ wk, const float* __restrict__ bk,
    const float* __restrict__ wv, const float* __restrict__ bv,
    float* __restrict__ Q, float* __restrict__ K, float* __restrict__ V)
{
    int idx = blockIdx.x * 256 + threadIdx.x;        // grid covers exactly 401408
    int ij = idx % NPOS;
    int oc = (idx / NPOS) & 127;
    int b  = idx / (NPOS * 128);

    float x0 = x[(b * 3 + 0) * NPOS + ij];
    float x1 = x[(b * 3 + 1) * NPOS + ij];
    float x2 = x[(b * 3 + 2) * NPOS + ij];

    float q = bq[oc] + wq[oc*3+0]*x0 + wq[oc*3+1]*x1 + wq[oc*3+2]*x2;
    float k = bk[oc] + wk[oc*3+0]*x0 + wk[oc*3+1]*x1 + wk[oc*3+2]*x2;
    float v = bv[oc] + wv[oc*3+0]*x0 + wv[oc*3+1]*x1 + wv[oc*3+2]*x2;

    int m = oc >> 3, h = oc & 7;                     // oc = m*HEADS + h
    int dst = ((b * 8 + h) * NPOS + ij) * 16 + m;
    Q[dst] = q; K[dst] = k; V[dst] = v;
}

// ---------------- kernel 2: attention, block = (b, ij), XCD-swizzled ----------------
// Wave w owns heads {w, w+4}, processed INTERLEAVED (two independent
// dependency chains per wave for latency hiding). No barriers in the body.
// Factorized softmax: p_g = ec[k] * er[g] * ecol[(g+1)&3].
__global__ __launch_bounds__(256, 4) void attn_kernel(
    const float* __restrict__ Q, const float* __restrict__ K, const float* __restrict__ V,
    const float* __restrict__ w_out, const float* __restrict__ b_out,
    const float* __restrict__ rw1, const float* __restrict__ rb1,
    const float* __restrict__ rga, const float* __restrict__ rbe,
    const float* __restrict__ rw2, const float* __restrict__ rb2,
    const float* __restrict__ cw1, const float* __restrict__ cb1,
    const float* __restrict__ cga, const float* __restrict__ cbe,
    const float* __restrict__ cw2, const float* __restrict__ cb2,
    float* __restrict__ out)
{
    __shared__ float          Er[8 * 110], Ec[8 * 110]; // embed tables, transposed [m][d]
    __shared__ unsigned short conth[4][2][800];         // [wave][head-slot][ch*50+s]: bf16 c -> ec
    __shared__ float4         RtE[4][2][56];            // exp'ed rotation terms
    __shared__ float          ovs[8][4][16];            // [h][g][m]

    const int t    = threadIdx.x;
    // XCD-aware swizzle (r11: halved FETCH_SIZE)
    const int b    = (blockIdx.x >> 1) & 3;
    const int ij   = (blockIdx.x >> 3) * 2 + (blockIdx.x & 1);
    const int iq   = ij / WDIM, jq = ij % WDIM;
    const int wave = t >> 6, lane = t & 63;
    const float scale = 0.57735026918962576f;        // 1/sqrt(CIN=3)

    // ---- embedding-MLP tables (once per block), transposed to [m][110] ----
    {
        int d = -1;
        const float *w1 = rw1, *b1 = rb1, *ga = rga, *be = rbe, *w2 = rw2, *b2 = rb2;
        float* E = Er;
        if (t < 110) { d = t; }
        else if (t >= 128 && t < 238) { d = t - 128; w1 = cw1; b1 = cb1; ga = cga; be = cbe; w2 = cw2; b2 = cb2; E = Ec; }
        if (d >= 0) {
            float u = (d < 55) ? (-1.0f + (float)d * (2.0f / 54.0f))
                               : -(-1.0f + (float)(d - 55) * (2.0f / 54.0f));
            float hb[16], mu = 0.0f;
#pragma unroll
            for (int c = 0; c < 16; ++c) { hb[c] = u * w1[c] + b1[c]; mu += hb[c]; }
            mu *= (1.0f / 16.0f);
            float var = 0.0f;
#pragma unroll
            for (int c = 0; c < 16; ++c) { float dv = hb[c] - mu; var += dv * dv; }
            var *= (1.0f / 16.0f);
            float rstd = rsqrtf(var + 1e-5f);
#pragma unroll
            for (int c = 0; c < 16; ++c) {
                float hn = ga[c] * (hb[c] - mu) * rstd + be[c];
                hb[c] = hn / (1.0f + __expf(-hn));
            }
#pragma unroll
            for (int m = 0; m < 8; ++m) {
                float e = b2[m];
#pragma unroll
                for (int c = 0; c < 16; ++c) e += hb[c] * w2[m * 16 + c];
                E[m * 110 + d] = e;                  // transposed
            }
        }
    }
    __syncthreads();                                 // E ready for all waves

    const int bh0 = b * 8 + wave;                    // head h0 = wave
    const int bh1 = bh0 + 4;                         // head h1 = wave + 4

    // q for both heads (wave-uniform loads, L2-hot)
    float q0[16], q1[16];
    {
        const float4* qp0 = (const float4*)(Q + (size_t)(bh0 * NPOS + ij) * 16);
        const float4* qp1 = (const float4*)(Q + (size_t)(bh1 * NPOS + ij) * 16);
#pragma unroll
        for (int r = 0; r < 4; ++r) {
            float4 a = qp0[r], c = qp1[r];
            q0[r*4+0]=a.x; q0[r*4+1]=a.y; q0[r*4+2]=a.z; q0[r*4+3]=a.w;
            q1[r*4+0]=c.x; q1[r*4+1]=c.y; q1[r*4+2]=c.z; q1[r*4+3]=c.w;
        }
    }

    // rotation terms for both heads + maxima -> exp'ed tables
    {
        float4 m0 = make_float4(-3.0e38f,-3.0e38f,-3.0e38f,-3.0e38f), m1 = m0;
        float4 r0, r1;
        if (lane < 55) {
            int d = lane;
            float a0=0,c0=0,a05=0,c05=0, a1=0,c1=0,a15=0,c15=0;
#pragma unroll
            for (int mm = 0; mm < 8; ++mm) {
                float er_ = Er[mm*110+d], er5 = Er[mm*110+d+55];
                float ec_ = Ec[mm*110+d], ec5 = Ec[mm*110+d+55];
                a0  += q0[mm]   * er_;  a05 += q0[mm]   * er5;
                c0  += q0[8+mm] * ec_;  c05 += q0[8+mm] * ec5;
                a1  += q1[mm]   * er_;  a15 += q1[mm]   * er5;
                c1  += q1[8+mm] * ec_;  c15 += q1[8+mm] * ec5;
            }
            r0 = make_float4(a0*scale, c0*scale, a05*scale, c05*scale);
            r1 = make_float4(a1*scale, c1*scale, a15*scale, c15*scale);
            m0 = r0; m1 = r1;
        }
#pragma unroll
        for (int off = 1; off < 64; off <<= 1) {
            m0.x = fmaxf(m0.x, __shfl_xor(m0.x, off, 64));
            m0.y = fmaxf(m0.y, __shfl_xor(m0.y, off, 64));
            m0.z = fmaxf(m0.z, __shfl_xor(m0.z, off, 64));
            m0.w = fmaxf(m0.w, __shfl_xor(m0.w, off, 64));
            m1.x = fmaxf(m1.x, __shfl_xor(m1.x, off, 64));
            m1.y = fmaxf(m1.y, __shfl_xor(m1.y, off, 64));
            m1.z = fmaxf(m1.z, __shfl_xor(m1.z, off, 64));
            m1.w = fmaxf(m1.w, __shfl_xor(m1.w, off, 64));
        }
        if (lane < 55) {
            RtE[wave][0][lane] = make_float4(__expf(r0.x-m0.x), __expf(r0.y-m0.y),
                                             __expf(r0.z-m0.z), __expf(r0.w-m0.w));
            RtE[wave][1][lane] = make_float4(__expf(r1.x-m1.x), __expf(r1.y-m1.y),
                                             __expf(r1.z-m1.z), __expf(r1.w-m1.w));
        }
    }

    // content pass, both heads interleaved -> bf16 strips; track maxima
    float maxc0 = -3.0e38f, maxc1 = -3.0e38f;
#pragma unroll 2
    for (int it = 0; it < 13; ++it) {
        int k = it * 64 + lane;
        if (k < NPOS) {
            const float4* kp0 = (const float4*)(K + (size_t)(bh0 * NPOS + k) * 16);
            const float4* kp1 = (const float4*)(K + (size_t)(bh1 * NPOS + k) * 16);
            float4 a0 = kp0[0], a1 = kp0[1], a2 = kp0[2], a3 = kp0[3];
            float4 d0 = kp1[0], d1 = kp1[1], d2 = kp1[2], d3 = kp1[3];
            float c0 = q0[0]*a0.x + q0[1]*a0.y + q0[2]*a0.z + q0[3]*a0.w
                     + q0[4]*a1.x + q0[5]*a1.y + q0[6]*a1.z + q0[7]*a1.w
                     + q0[8]*a2.x + q0[9]*a2.y + q0[10]*a2.z + q0[11]*a2.w
                     + q0[12]*a3.x + q0[13]*a3.y + q0[14]*a3.z + q0[15]*a3.w;
            float c1 = q1[0]*d0.x + q1[1]*d0.y + q1[2]*d0.z + q1[3]*d0.w
                     + q1[4]*d1.x + q1[5]*d1.y + q1[6]*d1.z + q1[7]*d1.w
                     + q1[8]*d2.x + q1[9]*d2.y + q1[10]*d2.z + q1[11]*d2.w
                     + q1[12]*d3.x + q1[13]*d3.y + q1[14]*d3.z + q1[15]*d3.w;
            c0 *= scale; c1 *= scale;
            int sidx = (k & 15) * 50 + (k >> 4);
            conth[wave][0][sidx] = (unsigned short)f2bf(c0);
            conth[wave][1][sidx] = (unsigned short)f2bf(c1);
            maxc0 = fmaxf(maxc0, c0); maxc1 = fmaxf(maxc1, c1);
        }
    }
#pragma unroll
    for (int off = 1; off < 64; off <<= 1) {
        maxc0 = fmaxf(maxc0, __shfl_xor(maxc0, off, 64));
        maxc1 = fmaxf(maxc1, __shfl_xor(maxc1, off, 64));
    }

    // exp-ify both strips (same-wave RMW, in-order, no barrier)
#pragma unroll 2
    for (int it = 0; it < 13; ++it) {
        int idx = it * 64 + lane;
        if (idx < 800) {
            float v0 = bflo((unsigned int)conth[wave][0][idx]);
            float v1 = bflo((unsigned int)conth[wave][1][idx]);
            conth[wave][0][idx] = (unsigned short)f2bf(__expf(v0 - maxc0));
            conth[wave][1][idx] = (unsigned short)f2bf(__expf(v1 - maxc1));
        }
    }

    // PV, both heads interleaved: lane = (vq = lane>>4, ch = lane&15)
    const int vq = lane >> 4, ch = lane & 15;
    const unsigned short* ecw0 = &conth[wave][0][ch * 50];
    const unsigned short* ecw1 = &conth[wave][1][ch * 50];
    const float4* Rp0 = &RtE[wave][0][0];
    const float4* Rp1 = &RtE[wave][1][0];
    float accA[4][4], accB[4][4];
#pragma unroll
    for (int g = 0; g < 4; ++g)
#pragma unroll
        for (int c = 0; c < 4; ++c) { accA[g][c] = 0.0f; accB[g][c] = 0.0f; }
    float psA0=0,psA1=0,psA2=0,psA3=0, psB0=0,psB1=0,psB2=0,psB3=0;
#pragma unroll 2
    for (int s = 0; s < 49; ++s) {
        int k   = s * 16 + ch;
        int row = (k * 2341) >> 16;                  // k / 28 (exact for k < 784)
        int col = k - row * WDIM;
        int dr  = row - iq + 27, dc = col - jq + 27;
        float  ecA  = bflo((unsigned int)ecw0[s]);
        float  ecB  = bflo((unsigned int)ecw1[s]);
        float4 erA  = Rp0[dr], ecolA = Rp0[dc];
        float4 erB  = Rp1[dr], ecolB = Rp1[dc];
        float pA0 = ecA*erA.x*ecolA.y, pA1 = ecA*erA.y*ecolA.z;
        float pA2 = ecA*erA.z*ecolA.w, pA3 = ecA*erA.w*ecolA.x;
        float pB0 = ecB*erB.x*ecolB.y, pB1 = ecB*erB.y*ecolB.z;
        float pB2 = ecB*erB.z*ecolB.w, pB3 = ecB*erB.w*ecolB.x;
        psA0 += pA0; psA1 += pA1; psA2 += pA2; psA3 += pA3;
        psB0 += pB0; psB1 += pB1; psB2 += pB2; psB3 += pB3;
        float4 vA = ((const float4*)(V + (size_t)(bh0 * NPOS + k) * 16))[vq];
        float4 vB = ((const float4*)(V + (size_t)(bh1 * NPOS + k) * 16))[vq];
        accA[0][0] += pA0*vA.x; accA[0][1] += pA0*vA.y; accA[0][2] += pA0*vA.z; accA[0][3] += pA0*vA.w;
        accA[1][0] += pA1*vA.x; accA[1][1] += pA1*vA.y; accA[1][2] += pA1*vA.z; accA[1][3] += pA1*vA.w;
        accA[2][0] += pA2*vA.x; accA[2][1] += pA2*vA.y; accA[2][2] += pA2*vA.z; accA[2][3] += pA2*vA.w;
        accA[3][0] += pA3*vA.x; accA[3][1] += pA3*vA.y; accA[3][2] += pA3*vA.z; accA[3][3] += pA3*vA.w;
        accB[0][0] += pB0*vB.x; accB[0][1] += pB0*vB.y; accB[0][2] += pB0*vB.z; accB[0][3] += pB0*vB.w;
        accB[1][0] += pB1*vB.x; accB[1][1] += pB1*vB.y; accB[1][2] += pB1*vB.z; accB[1][3] += pB1*vB.w;
        accB[2][0] += pB2*vB.x; accB[2][1] += pB2*vB.y; accB[2][2] += pB2*vB.z; accB[2][3] += pB2*vB.w;
        accB[3][0] += pB3*vB.x; accB[3][1] += pB3*vB.y; accB[3][2] += pB3*vB.z; accB[3][3] += pB3*vB.w;
    }
    // reduce over the 16 ch lanes (xor stays within each vq group)
#pragma unroll
    for (int off = 1; off < 16; off <<= 1) {
        psA0 += __shfl_xor(psA0, off, 64); psA1 += __shfl_xor(psA1, off, 64);
        psA2 += __shfl_xor(psA2, off, 64); psA3 += __shfl_xor(psA3, off, 64);
        psB0 += __shfl_xor(psB0, off, 64); psB1 += __shfl_xor(psB1, off, 64);
        psB2 += __shfl_xor(psB2, off, 64); psB3 += __shfl_xor(psB3, off, 64);
#pragma unroll
        for (int g = 0; g < 4; ++g)
#pragma unroll
            for (int c = 0; c < 4; ++c) {
                accA[g][c] += __shfl_xor(accA[g][c], off, 64);
                accB[g][c] += __shfl_xor(accB[g][c], off, 64);
            }
    }
    if (ch == 0) {
        float iA0 = 1.0f/psA0, iA1 = 1.0f/psA1, iA2 = 1.0f/psA2, iA3 = 1.0f/psA3;
        float iB0 = 1.0f/psB0, iB1 = 1.0f/psB1, iB2 = 1.0f/psB2, iB3 = 1.0f/psB3;
#pragma unroll
        for (int c = 0; c < 4; ++c) {
            ovs[wave][0][vq*4+c]   = accA[0][c]*iA0;
            ovs[wave][1][vq*4+c]   = accA[1][c]*iA1;
            ovs[wave][2][vq*4+c]   = accA[2][c]*iA2;
            ovs[wave][3][vq*4+c]   = accA[3][c]*iA3;
            ovs[wave+4][0][vq*4+c] = accB[0][c]*iB0;
            ovs[wave+4][1][vq*4+c] = accB[1][c]*iB1;
            ovs[wave+4][2][vq*4+c] = accB[2][c]*iB2;
            ovs[wave+4][3][vq*4+c] = accB[3][c]*iB3;
        }
    }
    __syncthreads();                                 // all ovs ready

    // ---- output projection: thread = (o = t>>2, g = t&3); out (B,64,G,28,28) ----
    {
        int o = t >> 2, g = t & 3;
        float acc = b_out[o];
        const float4* wr = (const float4*)(w_out + o * 128);
#pragma unroll
        for (int c4 = 0; c4 < 32; ++c4) {
            float4 w4 = wr[c4];
            int c = c4 * 4;                          // mh = m*8 + h
            acc += w4.x * ovs[(c    ) & 7][g][(c    ) >> 3];
            acc += w4.y * ovs[(c + 1) & 7][g][(c + 1) >> 3];
            acc += w4.z * ovs[(c + 2) & 7][g][(c + 2) >> 3];
            acc += w4.w * ovs[(c + 3) & 7][g][(c + 3) >> 3];
        }
        out[((b * 64 + o) * 4 + g) * NPOS + ij] = acc;
    }
}

extern "C" void kernel_launch(void* const* d_in, const int* in_sizes, int n_in,
                              void* d_out, int out_size, void* d_ws, size_t ws_size,
                              hipStream_t stream)
{
    const float* x     = (const float*)d_in[0];
    const float* wq    = (const float*)d_in[1];
    const float* bq    = (const float*)d_in[2];
    const float* wk    = (const float*)d_in[3];
    const float* bk    = (const float*)d_in[4];
    const float* wv    = (const float*)d_in[5];
    const float* bv    = (const float*)d_in[6];
    const float* w_out = (const float*)d_in[7];
    const float* b_out = (const float*)d_in[8];
    const float* rw1 = (const float*)d_in[9];
    const float* rb1 = (const float*)d_in[10];
    const float* rga = (const float*)d_in[11];
    const float* rbe = (const float*)d_in[12];
    const float* rw2 = (const float*)d_in[13];
    const float* rb2 = (const float*)d_in[14];
    const float* cw1 = (const float*)d_in[15];
    const float* cb1 = (const float*)d_in[16];
    const float* cga = (const float*)d_in[17];
    const float* cbe = (const float*)d_in[18];
    const float* cw2 = (const float*)d_in[19];
    const float* cb2 = (const float*)d_in[20];
    // d_in[21]/d_in[22] (ridx/cidx) unused: closed-form rotation indices.

    float* Q = (float*)d_ws;                 // 3 x 401408 floats = 4.8 MB
    float* K = Q + 401408;
    float* V = K + 401408;

    qkv_kernel<<<1568, 256, 0, stream>>>(x, wq, bq, wk, bk, wv, bv, Q, K, V);
    attn_kernel<<<4 * NPOS, 256, 0, stream>>>(
        Q, K, V, w_out, b_out,
        rw1, rb1, rga, rbe, rw2, rb2,
        cw1, cb1, cga, cbe, cw2, cb2,
        (float*)d_out);
}